// Round 1
// baseline (68444.891 us; speedup 1.0000x reference)
//
#include <hip/hip_runtime.h>
#include <hip/hip_fp16.h>
#include <math.h>

// LSTM_11089605558768: T=16384 sequential steps, H=512, IN=32, OUT=1.
// Persistent scan, 32 worker wgs x 256 threads.
//
// R7 (base = R6, 28.6ms):
//  Latency-bound on the LLC h-exchange (VALUBusy 2.3%, occ 1.5%). Two changes:
//  1. Per-wave self-contained gate layout: lane=(gate,hi,kq); each wave owns 4
//     h-elements end-to-end. Removes barrier C + LDS reduce + wave0-serial
//     epilogue; activation parallel over all 256 threads; publish fires
//     ~200-300cy earlier. One barrier/step; hshm parity-double-buffered.
//  2. Staggered 4-team polling with LDS-flag early exit: all 4 waves poll all
//     512 packets, first probe offset by s_sleep(0/2/4/6); while a load is in
//     flight the wave spins on an LDS flag (granularity ~40cy) instead of
//     vmcnt(0). Winner stages h + sets flag; losers leave the load dangling
//     (dest VGPRs kept live via "+v" constraints; drained pre-publish where
//     the wait is free). Union sampling period ~165cy vs 650cy blind grid.

#define T_STEPS 16384
#define IN_DIM  32
#define H_DIM   512
#define SLOTS   32
#define H_SLICE 16      // H_DIM / SLOTS
#define KTOT    544     // H_DIM + IN_DIM
#define CH      136     // KTOT / 4 (per kq lane)
#define SPIN    16      // flag-spin iterations (~load latency)

typedef unsigned int uint32x4 __attribute__((ext_vector_type(4)));

__device__ __forceinline__ float fast_sigmoid(float v) {
  return 1.0f / (1.0f + __expf(-v));
}
__device__ __forceinline__ float fast_tanh(float v) {
  return 2.0f / (1.0f + __expf(-2.0f * v)) - 1.0f;  // 2*sigmoid(2x)-1
}

// --- packet I/O (always LLC-coherent: sc0 sc1) -----------------------------
__device__ __forceinline__ void store_pkt(unsigned int* p, unsigned int v) {
  asm volatile("global_store_dword %0, %1, off sc0 sc1"
               :: "v"(p), "v"(v) : "memory");
}
__device__ __forceinline__ uint32x4 load_pkt4(const unsigned int* p) {
  uint32x4 r;
  asm volatile("global_load_dwordx4 %0, %1, off sc0 sc1\n\ts_waitcnt vmcnt(0)"
               : "=&v"(r) : "v"(p) : "memory");
  return r;
}
__device__ __forceinline__ float pkt_to_f(unsigned int v) {
  return __half2float(__ushort_as_half((unsigned short)(v & 0xFFFFu)));
}

__launch_bounds__(256, 1)
__global__ void lstm_scan_kernel(
    const float* __restrict__ x,     // [T, 32]
    const float* __restrict__ Wih,   // [2048, 32]
    const float* __restrict__ Whh,   // [2048, 512]
    const float* __restrict__ bih,   // [2048]
    const float* __restrict__ bhh,   // [2048]
    const float* __restrict__ Wlin,  // [512]
    const float* __restrict__ blin,  // [1]
    float* __restrict__ out,         // [1]
    unsigned int* pub)               // [2][512] 4B packets (d_ws)
{
  const int slot = blockIdx.x;       // 0..31
  const int tid  = threadIdx.x;
  const int w    = tid >> 6;         // wave 0..3 -> owns h sub-block w*4..w*4+3
  const int l    = tid & 63;

  // lane decomposition: gate (i,f,g,o), hi (h within wave's 4), kq (k-chunk)
  const int gate = l >> 4;
  const int hi   = (l >> 2) & 3;
  const int kq   = l & 3;

  // parity-double-buffered h(+x) staging: [parity][0,512)=h, [512,544)=x
  __shared__ __align__(16) float buf[2][KTOT];
  __shared__ float red[256];          // epilogue only
  __shared__ volatile int flag;       // == t when h(t) staged into buf[t&1]

  const int R = gate * H_DIM + slot * H_SLICE + w * 4 + hi;  // global gate row

  // Persistent weight slice -> registers, PINNED with opaque asm identity
  // (proven R6 fix: compiler otherwise re-streams from L2 every step).
  float wreg[CH];
  #pragma unroll
  for (int j = 0; j < CH; ++j) {
    const int k = kq * CH + j;
    wreg[j] = (k < H_DIM) ? Whh[R * H_DIM + k]
                          : Wih[R * IN_DIM + (k - H_DIM)];
  }
  #pragma unroll
  for (int j = 0; j < CH; ++j)
    asm volatile("v_mov_b32 %0, %0" : "+v"(wreg[j]));

  const float bias = bih[R] + bhh[R];
  float c = 0.0f;  // cell state for h index slot*16 + w*4 + hi (lane-replicated)

  const bool own_lane = ((l >> 1) == slot);  // this lane's 8 packets == own slot
  const bool xthr = (tid < IN_DIM);

  if (tid < H_SLICE) buf[0][slot * H_SLICE + tid] = 0.0f;  // h(0) own slice fp32
  if (tid == 0) flag = -1;
  __syncthreads();

  // Poll destination regs: must stay live across iterations (dangling loads).
  uint32x4 pr0 = {0, 0, 0, 0}, pr1 = {0, 0, 0, 0};

  for (int t = 0; t < T_STEPS; ++t) {
    // x_t load issues early; consumed (LDS write) after the poll resolves.
    float xv = xthr ? x[t * IN_DIM + tid] : 0.0f;

    const unsigned int tg = (unsigned int)t & 0xFFFFu;
    const unsigned int* pp = pub + (t & 1) * H_DIM + l * 8;

    // ---- gather h(t): 4 staggered teams, LDS-flag early exit ----
    if (flag != t) {
      // one-time phase offset per wave (64cy units); winner sets flag long
      // after 384cy in the common case, so the sleep is absorbed.
      if      (w == 1) __builtin_amdgcn_s_sleep(2);
      else if (w == 2) __builtin_amdgcn_s_sleep(4);
      else if (w == 3) __builtin_amdgcn_s_sleep(6);
      for (;;) {
        if (flag == t) break;  // another team staged it; loads left dangling
        asm volatile("global_load_dwordx4 %0, %2, off sc0 sc1\n\t"
                     "global_load_dwordx4 %1, %2, off offset:16 sc0 sc1"
                     : "+v"(pr0), "+v"(pr1) : "v"(pp) : "memory");
        int fastexit = 0;
        #pragma unroll 1
        for (int s2 = 0; s2 < SPIN; ++s2) {
          if (flag == t) { fastexit = 1; break; }   // ~40cy granularity
        }
        if (fastexit) break;                        // dangling loads in flight
        asm volatile("s_waitcnt vmcnt(0)"
                     : "+v"(pr0), "+v"(pr1) :: "memory");
        const bool ok = own_lane ||
            ((pr0.x >> 16) == tg && (pr0.y >> 16) == tg &&
             (pr0.z >> 16) == tg && (pr0.w >> 16) == tg &&
             (pr1.x >> 16) == tg && (pr1.y >> 16) == tg &&
             (pr1.z >> 16) == tg && (pr1.w >> 16) == tg);
        if (__all(ok)) {
          if (!own_lane) {  // own slice already fp32 from publisher
            float4 ha, hb;
            ha.x = pkt_to_f(pr0.x); ha.y = pkt_to_f(pr0.y);
            ha.z = pkt_to_f(pr0.z); ha.w = pkt_to_f(pr0.w);
            hb.x = pkt_to_f(pr1.x); hb.y = pkt_to_f(pr1.y);
            hb.z = pkt_to_f(pr1.z); hb.w = pkt_to_f(pr1.w);
            *(float4*)(&buf[t & 1][l * 8])     = ha;
            *(float4*)(&buf[t & 1][l * 8 + 4]) = hb;
          }
          if (l == 0) flag = t;
          break;
        }
      }
    }
    if (xthr) buf[t & 1][H_DIM + tid] = xv;
    __syncthreads();  // barrier B: h(t) + x_t staged (LDS visibility)

    // ---- matvec: lane covers row (gate,hi), k in [kq*136, kq*136+136) ----
    const float4* hv = (const float4*)(&buf[t & 1][kq * CH]);  // 544B-aligned
    float a0 = 0.f, a1 = 0.f, a2 = 0.f, a3 = 0.f;
    #pragma unroll
    for (int q = 0; q < CH / 4; ++q) {
      const float4 h4 = hv[q];  // 16-lane broadcast, 4 disjoint bank groups
      a0 = fmaf(wreg[4 * q + 0], h4.x, a0);
      a1 = fmaf(wreg[4 * q + 1], h4.y, a1);
      a2 = fmaf(wreg[4 * q + 2], h4.z, a2);
      a3 = fmaf(wreg[4 * q + 3], h4.w, a3);
    }
    float s = (a0 + a1) + (a2 + a3);
    s += __shfl_xor(s, 1, 64);   // reduce over kq
    s += __shfl_xor(s, 2, 64);
    const float g = s + bias;
    const float act = (gate == 2) ? fast_tanh(g) : fast_sigmoid(g);

    // gather i,f,g,o for this lane's hi (all kq copies identical)
    const int base = l & 15;     // hi*4 + kq
    const float ig = __shfl(act, base,      64);
    const float fg = __shfl(act, base + 16, 64);
    const float gt = __shfl(act, base + 32, 64);
    const float og = __shfl(act, base + 48, 64);
    c = fg * c + ig * gt;
    const float h = og * fast_tanh(c);

    // Drain dangling poll loads here (they're long done) so the publish
    // store's ack never blocks the next poll's load issue.
    asm volatile("s_waitcnt vmcnt(0)" : "+v"(pr0), "+v"(pr1) :: "memory");

    // ---- publish: lanes (gate==0, kq==0), 4 per wave ----
    if (gate == 0 && kq == 0) {
      const int hidx = slot * H_SLICE + w * 4 + hi;
      buf[(t + 1) & 1][hidx] = h;  // own-slice fp32 shortcut for next step
      const unsigned int pkt =
          (((unsigned int)(t + 1) & 0xFFFFu) << 16) |
          (unsigned int)__half_as_ushort(__float2half_rn(h));
      store_pkt(pub + ((t + 1) & 1) * H_DIM + hidx, pkt);
    }
    // buf[(t+1)&1] writes (publisher fp32 + next poll's winner) are disjoint
    // from buf[t&1] readers; cross-step reuse is separated by barrier B.
  }

  // final drain: keep pr regs reserved until all danglers have landed
  asm volatile("s_waitcnt vmcnt(0)" : "+v"(pr0), "+v"(pr1) :: "memory");

  // ---- slot 0: final projection out = h(T) . Wlin + blin ----
  if (slot != 0) return;
  if (w == 0) {
    // parity of T_STEPS is 0; lanes 0,1 cover own slot (already fp32)
    const unsigned int* p = pub + l * 8;
    const unsigned int tg = (unsigned int)T_STEPS & 0xFFFFu;
    if (l >= 2) {
      for (;;) {
        uint32x4 r0 = load_pkt4(p);
        uint32x4 r1 = load_pkt4(p + 4);
        if ((r0.x >> 16) == tg && (r0.y >> 16) == tg &&
            (r0.z >> 16) == tg && (r0.w >> 16) == tg &&
            (r1.x >> 16) == tg && (r1.y >> 16) == tg &&
            (r1.z >> 16) == tg && (r1.w >> 16) == tg) {
          float4 ha, hb;
          ha.x = pkt_to_f(r0.x); ha.y = pkt_to_f(r0.y);
          ha.z = pkt_to_f(r0.z); ha.w = pkt_to_f(r0.w);
          hb.x = pkt_to_f(r1.x); hb.y = pkt_to_f(r1.y);
          hb.z = pkt_to_f(r1.z); hb.w = pkt_to_f(r1.w);
          *(float4*)(&buf[0][l * 8])     = ha;
          *(float4*)(&buf[0][l * 8 + 4]) = hb;
          break;
        }
      }
    }
  }
  __syncthreads();
  red[tid] = buf[0][2 * tid] * Wlin[2 * tid] +
             buf[0][2 * tid + 1] * Wlin[2 * tid + 1];
  __syncthreads();
  if (w == 0) {
    float s2 = red[l] + red[64 + l] + red[128 + l] + red[192 + l];
    #pragma unroll
    for (int off = 32; off > 0; off >>= 1) s2 += __shfl_down(s2, off, 64);
    if (l == 0) out[0] = s2 + blin[0];
  }
}

extern "C" void kernel_launch(void* const* d_in, const int* in_sizes, int n_in,
                              void* d_out, int out_size, void* d_ws, size_t ws_size,
                              hipStream_t stream) {
  const float* x    = (const float*)d_in[0];
  const float* Wih  = (const float*)d_in[1];
  const float* Whh  = (const float*)d_in[2];
  const float* bih  = (const float*)d_in[3];
  const float* bhh  = (const float*)d_in[4];
  const float* Wlin = (const float*)d_in[5];
  const float* blin = (const float*)d_in[6];
  float* out = (float*)d_out;

  unsigned int* pub = (unsigned int*)d_ws;  // [2][512] u32 = 4096 B

  // d_ws re-poisoned before every timed call; zeroed pub encodes
  // (tag=0, h=0) == the initial hidden state h(0).
  hipMemsetAsync(d_ws, 0, 4096, stream);
  hipLaunchKernelGGL(lstm_scan_kernel, dim3(SLOTS), dim3(256), 0, stream,
                     x, Wih, Whh, bih, bhh, Wlin, blin, out, pub);
}

// Round 2
// 34352.020 us; speedup vs baseline: 1.9925x; 1.9925x over previous
//
#include <hip/hip_runtime.h>
#include <hip/hip_fp16.h>
#include <math.h>

// LSTM_11089605558768: T=16384 sequential steps, H=512, IN=32, OUT=1.
// Persistent scan, 32 worker wgs x 256 threads.
//
// R8 (base = R6 @28.6ms; R7's poll restructure FALSIFIED: VGPR 144->96 =
// weight pin broke -> 32MB/dispatch scratch spill (WRITE_SIZE 2x), plus
// stride-32B ds_write_b128 winner staging = 2.9e7 bank conflicts).
// R8 keeps R6's PROVEN polling verbatim (blind vmcnt(0) polls, 128 pollers,
// contiguous tid*4 staging = 0 conflicts) and applies only R7's epilogue
// remap, which adds no live state:
//   lane = (gate, hi, kq); each wave owns h sub-block w*4..w*4+3 end-to-end.
//   k-reduce = 2 shfl_xor; gate gather = 4 shfl; activation on all 256
//   threads; publish from 4 lanes/wave fires ~200cy earlier than R6's
//   wave0-serial epilogue. Removes barrier C + red[] LDS round-trip.
//   One barrier/step; buf parity-double-buffered (barrier B(t+1) separates
//   all parity-p writers of step t+1 from parity-p readers of step t).

#define T_STEPS 16384
#define IN_DIM  32
#define H_DIM   512
#define SLOTS   32
#define H_SLICE 16      // H_DIM / SLOTS
#define KTOT    544     // H_DIM + IN_DIM
#define CH      136     // KTOT / 4 (per kq lane)

typedef unsigned int uint32x4 __attribute__((ext_vector_type(4)));

__device__ __forceinline__ float fast_sigmoid(float v) {
  return 1.0f / (1.0f + __expf(-v));
}
__device__ __forceinline__ float fast_tanh(float v) {
  return 2.0f / (1.0f + __expf(-2.0f * v)) - 1.0f;  // 2*sigmoid(2x)-1
}

// --- packet I/O (always LLC-coherent: sc0 sc1) -----------------------------
__device__ __forceinline__ void store_pkt(unsigned int* p, unsigned int v) {
  asm volatile("global_store_dword %0, %1, off sc0 sc1"
               :: "v"(p), "v"(v) : "memory");
}
__device__ __forceinline__ uint32x4 load_pkt4(const unsigned int* p) {
  uint32x4 r;
  asm volatile("global_load_dwordx4 %0, %1, off sc0 sc1\n\ts_waitcnt vmcnt(0)"
               : "=&v"(r) : "v"(p) : "memory");
  return r;
}
__device__ __forceinline__ float pkt_to_f(unsigned int v) {
  return __half2float(__ushort_as_half((unsigned short)(v & 0xFFFFu)));
}

__launch_bounds__(256, 1)
__global__ void lstm_scan_kernel(
    const float* __restrict__ x,     // [T, 32]
    const float* __restrict__ Wih,   // [2048, 32]
    const float* __restrict__ Whh,   // [2048, 512]
    const float* __restrict__ bih,   // [2048]
    const float* __restrict__ bhh,   // [2048]
    const float* __restrict__ Wlin,  // [512]
    const float* __restrict__ blin,  // [1]
    float* __restrict__ out,         // [1]
    unsigned int* pub)               // [2][512] 4B packets (d_ws)
{
  const int slot = blockIdx.x;       // 0..31
  const int tid  = threadIdx.x;
  const int w    = tid >> 6;         // wave 0..3 -> owns h sub-block w*4..w*4+3
  const int l    = tid & 63;

  // lane decomposition: gate (i,f,g,o), hi (h within wave's 4), kq (k-chunk)
  const int gate = l >> 4;
  const int hi   = (l >> 2) & 3;
  const int kq   = l & 3;

  // parity-double-buffered staging: [parity][0,512)=h(t), [512,544)=x_t
  __shared__ __align__(16) float buf[2][KTOT];
  __shared__ float red[256];          // final projection only

  const int R = gate * H_DIM + slot * H_SLICE + w * 4 + hi;  // global gate row

  // Persistent weight slice -> registers, PINNED with opaque asm identity
  // (proven R6 fix: compiler otherwise re-streams from L2 every step).
  float wreg[CH];
  #pragma unroll
  for (int j = 0; j < CH; ++j) {
    const int k = kq * CH + j;
    wreg[j] = (k < H_DIM) ? Whh[R * H_DIM + k]
                          : Wih[R * IN_DIM + (k - H_DIM)];
  }
  #pragma unroll
  for (int j = 0; j < CH; ++j)
    asm volatile("v_mov_b32 %0, %0" : "+v"(wreg[j]));

  const float bias = bih[R] + bhh[R];
  float c = 0.0f;  // cell state for h index slot*16+w*4+hi (replicated x16 lanes)

  // Polling assignment (R6-proven): tid<128 polls packets [4*tid, 4*tid+4);
  // own-slot group skipped (publishers provide it in fp32).
  const bool poller = (tid < 128) && ((tid >> 2) != slot);
  const bool xthr   = (tid < IN_DIM);

  if (tid < H_SLICE) buf[0][slot * H_SLICE + tid] = 0.0f;  // h(0) own slice

  for (int t = 0; t < T_STEPS; ++t) {
    // x_t load overlaps the poll (independent; consumed after poll resolves)
    float xv = xthr ? x[t * IN_DIM + tid] : 0.0f;

    // ---- gather h(t): blind poll, 4 self-validating packets per thread ----
    if (poller) {
      const unsigned int* p = pub + (t & 1) * H_DIM + tid * 4;
      const unsigned int tg = (unsigned int)t & 0xFFFFu;
      uint32x4 r;
      for (;;) {
        r = load_pkt4(p);
        if ((r.x >> 16) == tg && (r.y >> 16) == tg &&
            (r.z >> 16) == tg && (r.w >> 16) == tg) break;
      }
      float4 hv4;
      hv4.x = pkt_to_f(r.x);
      hv4.y = pkt_to_f(r.y);
      hv4.z = pkt_to_f(r.z);
      hv4.w = pkt_to_f(r.w);
      *(float4*)(&buf[t & 1][tid * 4]) = hv4;  // contiguous: 0 bank conflicts
    }
    if (xthr) buf[t & 1][H_DIM + tid] = xv;
    __syncthreads();  // barrier B: h(t) + x_t staged (the only per-step barrier)

    // ---- matvec: lane covers row (gate,hi), k in [kq*136, kq*136+136) ----
    const float4* hv = (const float4*)(&buf[t & 1][kq * CH]);  // 544B-aligned
    float a0 = 0.f, a1 = 0.f, a2 = 0.f, a3 = 0.f;
    #pragma unroll
    for (int q = 0; q < CH / 4; ++q) {
      const float4 h4 = hv[q];  // 16-lane broadcast, 4 disjoint bank quads
      a0 = fmaf(wreg[4 * q + 0], h4.x, a0);
      a1 = fmaf(wreg[4 * q + 1], h4.y, a1);
      a2 = fmaf(wreg[4 * q + 2], h4.z, a2);
      a3 = fmaf(wreg[4 * q + 3], h4.w, a3);
    }
    float s = (a0 + a1) + (a2 + a3);
    s += __shfl_xor(s, 1, 64);   // reduce over kq (4-lane groups)
    s += __shfl_xor(s, 2, 64);
    const float g = s + bias;
    const float act = (gate == 2) ? fast_tanh(g) : fast_sigmoid(g);

    // gather i,f,g,o for this lane's hi (act replicated across kq)
    const int base = l & 15;     // hi*4 + kq
    const float ig = __shfl(act, base,      64);
    const float fg = __shfl(act, base + 16, 64);
    const float gt = __shfl(act, base + 32, 64);
    const float og = __shfl(act, base + 48, 64);
    c = fg * c + ig * gt;
    const float h = og * fast_tanh(c);

    // ---- publish: lanes (gate==0, kq==0), 4 per wave, all waves parallel ----
    if (gate == 0 && kq == 0) {
      const int hidx = slot * H_SLICE + w * 4 + hi;
      buf[(t + 1) & 1][hidx] = h;  // own-slice fp32 shortcut for next step
      const unsigned int pkt =
          (((unsigned int)(t + 1) & 0xFFFFu) << 16) |
          (unsigned int)__half_as_ushort(__float2half_rn(h));
      store_pkt(pub + ((t + 1) & 1) * H_DIM + hidx, pkt);
    }
    // Parity hazards: all parity-(t+1) writes (publish fp32 + next poll's
    // staging) are ordered after every parity-(t+1)... reader of step t-1 by
    // barrier B(t); parity-(t&1) rewrites at t+2 are ordered after matvec-t
    // reads by barrier B(t+1). Single barrier per step is sufficient.
  }

  // ---- slot 0: final projection out = h(T) . Wlin + blin ----
  if (slot != 0) return;
  if (poller) {  // gather h(T) (parity T&1 == 0); own slice already fp32
    const unsigned int* p = pub + (T_STEPS & 1) * H_DIM + tid * 4;
    const unsigned int tg = (unsigned int)T_STEPS & 0xFFFFu;
    uint32x4 r;
    for (;;) {
      r = load_pkt4(p);
      if ((r.x >> 16) == tg && (r.y >> 16) == tg &&
          (r.z >> 16) == tg && (r.w >> 16) == tg) break;
    }
    float4 hv4;
    hv4.x = pkt_to_f(r.x);
    hv4.y = pkt_to_f(r.y);
    hv4.z = pkt_to_f(r.z);
    hv4.w = pkt_to_f(r.w);
    *(float4*)(&buf[0][tid * 4]) = hv4;
  }
  __syncthreads();
  red[tid] = buf[0][2 * tid] * Wlin[2 * tid] +
             buf[0][2 * tid + 1] * Wlin[2 * tid + 1];
  __syncthreads();
  if (w == 0) {
    float s2 = red[l] + red[64 + l] + red[128 + l] + red[192 + l];
    #pragma unroll
    for (int off = 32; off > 0; off >>= 1) s2 += __shfl_down(s2, off, 64);
    if (l == 0) out[0] = s2 + blin[0];
  }
}

extern "C" void kernel_launch(void* const* d_in, const int* in_sizes, int n_in,
                              void* d_out, int out_size, void* d_ws, size_t ws_size,
                              hipStream_t stream) {
  const float* x    = (const float*)d_in[0];
  const float* Wih  = (const float*)d_in[1];
  const float* Whh  = (const float*)d_in[2];
  const float* bih  = (const float*)d_in[3];
  const float* bhh  = (const float*)d_in[4];
  const float* Wlin = (const float*)d_in[5];
  const float* blin = (const float*)d_in[6];
  float* out = (float*)d_out;

  unsigned int* pub = (unsigned int*)d_ws;  // [2][512] u32 = 4096 B

  // d_ws re-poisoned before every timed call; zeroed pub encodes
  // (tag=0, h=0) == the initial hidden state h(0).
  hipMemsetAsync(d_ws, 0, 4096, stream);
  hipLaunchKernelGGL(lstm_scan_kernel, dim3(SLOTS), dim3(256), 0, stream,
                     x, Wih, Whh, bih, bhh, Wlin, blin, out, pub);
}